// Round 16
// baseline (495.247 us; speedup 1.0000x reference)
//
#include <hip/hip_runtime.h>
#include <cstddef>
#include <cstdint>

// Problem constants: EMBED=1024, NUM_HEADS=16, GQA=4, KV_HEADS=4,
// HEAD_DIM=64, KV_EMBED=256, EPS=1e-3, B=2, T=1024.
#define TSEQ 1024

typedef __attribute__((ext_vector_type(8))) short short8;   // 8 bf16 = 4 VGPRs
typedef __attribute__((ext_vector_type(4))) float floatx4;  // MFMA acc

// Workspace layout (floats):
//  XQ : 2048 x 1024  (2M)
//  XK : 2048 x 256   (0.5M)
//  XVt: 2 x 256 x 1024 (0.5M)  -- V-projection TRANSPOSED: [b][h*64+c][j]
//  XO : 2048 x 1024  (2M)
//  P  : 32 x 1024x1024 (33.55M) -- q=1-p / phi in GROUP-DIAGONAL-4 layout
static constexpr size_t OFF_XQ  = 0;
static constexpr size_t OFF_XK  = (size_t)2 * 1024 * 1024;
static constexpr size_t OFF_XVT = OFF_XK + (size_t)512 * 1024;
static constexpr size_t OFF_XO  = OFF_XVT + (size_t)512 * 1024;
static constexpr size_t OFF_P   = OFF_XO + (size_t)2 * 1024 * 1024;

// GROUP-DIAGONAL-4 LAYOUT (R21): logical cell (r, c) lives at storage row
//   diagrow4(r, c) = ((((r>>2) + (c>>2)) & 255) << 2) | (r & 3), column c.
// Bijective at 4MB/z: each (slot D, position u=c>>2) holds exactly one
// valid cell-group (the unique g = (D-u) mod 256), touched at its unique
// step s* = g+u (read as q, overwritten as phi). Same wrap argument as
// the 16-col layout; storage size unchanged.
//
// R21 mono: 4 SYMMETRIC waves per z (256 threads). Logical lane u = tid
// owns cols [4u, 4u+4); at step s handles rows 4g..4g+3, g = s-u; steps
// 0..511. Per wave per step: 4 float4 loads + 4 float4 stores (vs 32 in
// the single-wave R11) -- the per-wave outstanding-VMEM limit (~60cy per
// float4 instr, calibrated R6-R14: mono sat at its 8192-instr floor of
// ~205us) now splits across 4 waves: 512x8 = 4096 instr/wave ~ 102us
// floor. Rows stay intra-lane (serial 4-row chain never crosses waves);
// intra-wave boundary = 8 shfl_up as before; inter-wave boundary = 8
// floats via double-buffered LDS + ONE raw barrier/step (R17-proven
// MONO_BAR: lgkmcnt(0)+s_barrier only, NO vmcnt drain -- loads stay in
// flight). Unlike R15-R18 (which routed all 16KB/step through LDS and
// died on barrier/LDS costs), only 24 boundary floats cross waves.
// R20 (kept): fused in-projections (one 768-block launch), __expf
// sigmoid, 64x64 GEMM core everywhere.
// R11 (kept): q-form recurrence (scores stores q = 1-p), 2 fma/cell.

// ---------------------------------------------------------------------------
// fp32 -> bf16 hi/lo split (RNE). x ≈ hi + lo with residual ~2^-17 |x|.
// ---------------------------------------------------------------------------
__device__ __forceinline__ void cvt_hi_lo(float x, unsigned short& hi,
                                          unsigned short& lo) {
  unsigned u = __float_as_uint(x);
  unsigned rh = (u + 0x7FFFu + ((u >> 16) & 1u)) & 0xFFFF0000u;
  hi = (unsigned short)(rh >> 16);
  float xl = x - __uint_as_float(rh);
  unsigned ul = __float_as_uint(xl);
  unsigned rl = ul + 0x7FFFu + ((ul >> 16) & 1u);
  lo = (unsigned short)(rl >> 16);
}

__device__ __forceinline__ int diagrow4(int r, int c) {
  return ((((r >> 2) + (c >> 2)) & 255) << 2) | (r & 3);
}

typedef unsigned short lds_tile_t[40];

// ---------------------------------------------------------------------------
// Unified NT GEMM core, MFMA bf16x3, 64x64 tile (R5-proven; bm/bn + LDS
// arrays are parameters per R20). ADIAG: A read through diagrow4 (the
// 8-float staging run spans TWO storage rows -> two float4 bases).
// CDIAG: C row through diagrow4. EPI=2 writes q = sigmoid(-x) clipped.
// ---------------------------------------------------------------------------
template <int EPI, int ADIAG, int CDIAG>
__device__ __forceinline__ void mfma_nt_core(
    const float* __restrict__ A, int lda,
    const float* __restrict__ B, int ldb,
    float* __restrict__ C, int ldc, int K,
    const float* __restrict__ bias,
    int bm, int bn,
    lds_tile_t* __restrict__ Ah, lds_tile_t* __restrict__ Al,
    lds_tile_t* __restrict__ Bh, lds_tile_t* __restrict__ Bl)
{
  const int tid  = threadIdx.x;
  const int lane = tid & 63;
  const int wave = tid >> 6;        // 0..3 -> row sub-tile
  const int m16  = lane & 15;
  const int quad = lane >> 4;

  const int srow = tid >> 2;        // staging: row 0..63
  const int skq  = (tid & 3) << 3;  // staging: k offset 0,8,16,24

  floatx4 acc[4];
#pragma unroll
  for (int c = 0; c < 4; ++c) acc[c] = (floatx4){0.f, 0.f, 0.f, 0.f};

  for (int k0 = 0; k0 < K; k0 += 32) {
    {
      const int kq = k0 + skq;
      const float* ap;
      const float* ap2;
      if (ADIAG) {
        const int r  = bm + srow;
        const int a0 = diagrow4(r, kq);
        const int a1 = diagrow4(r, kq + 4);
        ap  = A + (size_t)a0 * lda + kq;
        ap2 = A + (size_t)a1 * lda + (kq + 4);
      } else {
        ap  = A + (size_t)(bm + srow) * lda + kq;
        ap2 = ap + 4;
      }
      const float* bp = B + (size_t)(bn + srow) * ldb + kq;
      float av[8] __attribute__((aligned(16)));
      float bv[8] __attribute__((aligned(16)));
      *(float4*)&av[0] = *(const float4*)(ap);
      *(float4*)&av[4] = *(const float4*)(ap2);
      *(float4*)&bv[0] = *(const float4*)(bp);
      *(float4*)&bv[4] = *(const float4*)(bp + 4);
      short8 vah, valo, vbh, vblo;
#pragma unroll
      for (int e = 0; e < 8; ++e) {
        unsigned short h, l;
        cvt_hi_lo(av[e], h, l);
        vah[e] = (short)h; valo[e] = (short)l;
        cvt_hi_lo(bv[e], h, l);
        vbh[e] = (short)h; vblo[e] = (short)l;
      }
      *(short8*)&Ah[srow][skq] = vah;
      *(short8*)&Al[srow][skq] = valo;
      *(short8*)&Bh[srow][skq] = vbh;
      *(short8*)&Bl[srow][skq] = vblo;
    }
    __syncthreads();

    const int arow = (wave << 4) + m16;
    const short8 a_h = *(const short8*)&Ah[arow][quad << 3];
    const short8 a_l = *(const short8*)&Al[arow][quad << 3];
#pragma unroll
    for (int c = 0; c < 4; ++c) {
      const int brow = (c << 4) + m16;
      const short8 b_h = *(const short8*)&Bh[brow][quad << 3];
      const short8 b_l = *(const short8*)&Bl[brow][quad << 3];
      acc[c] = __builtin_amdgcn_mfma_f32_16x16x32_bf16(a_h, b_h, acc[c], 0, 0, 0);
      acc[c] = __builtin_amdgcn_mfma_f32_16x16x32_bf16(a_h, b_l, acc[c], 0, 0, 0);
      acc[c] = __builtin_amdgcn_mfma_f32_16x16x32_bf16(a_l, b_h, acc[c], 0, 0, 0);
    }
    __syncthreads();
  }

#pragma unroll
  for (int c = 0; c < 4; ++c) {
#pragma unroll
    for (int r = 0; r < 4; ++r) {
      const int row = (wave << 4) + (quad << 2) + r;
      const int col = (c << 4) + m16;
      float v = acc[c][r];
      if (EPI == 0) { if (bias) v += bias[bn + col]; }
      if (EPI == 1) { v += bias[bm + row]; }
      if (EPI == 2) {
        // q = 1 - clip(sigmoid(v)) = clip(sigmoid(-v), 0.001, 0.999)
        v = 1.0f / (1.0f + __expf(v));
        v = fminf(fmaxf(v, 0.001f), 0.999f);
      }
      int crow = bm + row;
      if (CDIAG) crow = diagrow4(bm + row, bn + col);
      C[(size_t)crow * ldc + (bn + col)] = v;
    }
  }
}

#define DECL_GEMM_SMEM                                          \
  __shared__ __align__(16) unsigned short Ah[64][40];           \
  __shared__ __align__(16) unsigned short Al[64][40];           \
  __shared__ __align__(16) unsigned short Bh[64][40];           \
  __shared__ __align__(16) unsigned short Bl[64][40];

// ---------------------------------------------------------------------------
// Fused in-projections (R20): one 768-block launch.
// ---------------------------------------------------------------------------
__global__ __launch_bounds__(256) void inproj_k(
    const float* __restrict__ query, const float* __restrict__ key,
    const float* __restrict__ value, const float* __restrict__ ipw,
    const float* __restrict__ ipb,
    float* __restrict__ XQ, float* __restrict__ XK, float* __restrict__ XVt)
{
  DECL_GEMM_SMEM
  const int id = blockIdx.x;
  if (id < 512) {
    mfma_nt_core<0, 0, 0>(query, 1024, ipw, 1024, XQ, 1024, 1024, ipb,
                          (id >> 4) << 6, (id & 15) << 6, Ah, Al, Bh, Bl);
  } else if (id < 640) {
    const int j = id - 512;
    mfma_nt_core<0, 0, 0>(key, 1024, ipw + ((size_t)1 << 20), 1024,
                          XK, 256, 1024, ipb + 1024,
                          (j >> 2) << 6, (j & 3) << 6, Ah, Al, Bh, Bl);
  } else {
    const int j = id - 640;
    const int b = j >> 6;
    mfma_nt_core<1, 0, 0>(ipw + (size_t)1280 * 1024, 1024,
                          value + ((size_t)b << 20), 1024,
                          XVt + (size_t)b * 256 * 1024, 1024, 1024,
                          ipb + 1280,
                          ((j >> 4) & 3) << 6, (j & 15) << 6, Ah, Al, Bh, Bl);
  }
}

// out-projection (and generic NT GEMM), 64x64 tiles
__global__ __launch_bounds__(256) void gemm_nt_mfma_k(
    const float* __restrict__ A, int lda, const float* __restrict__ W, int ldw,
    const float* __restrict__ bias, float* __restrict__ C, int ldc, int K)
{
  DECL_GEMM_SMEM
  mfma_nt_core<0, 0, 0>(A, lda, W, ldw, C, ldc, K, bias,
                        blockIdx.y << 6, blockIdx.x << 6, Ah, Al, Bh, Bl);
}

// scores: writes q = 1-p in GROUP-DIAGONAL-4 layout (CDIAG=1)
__global__ __launch_bounds__(256) void scores_mfma_k(
    const float* __restrict__ XQ, const float* __restrict__ XK,
    float* __restrict__ P)
{
  DECL_GEMM_SMEM
  const int z = blockIdx.z;
  const int b = z >> 4;
  mfma_nt_core<2, 0, 1>(XQ + ((size_t)b << 20) + ((size_t)(z & 15) << 6), 1024,
                        XK + (size_t)b * TSEQ * 256 + ((size_t)(z & 3) << 6), 256,
                        P + ((size_t)z << 20), 1024, 64, nullptr,
                        blockIdx.y << 6, blockIdx.x << 6, Ah, Al, Bh, Bl);
}

// pv: reads phi (A) from GROUP-DIAGONAL-4 layout (ADIAG=1)
__global__ __launch_bounds__(256) void pv_mfma_k(
    const float* __restrict__ P, const float* __restrict__ XVt,
    float* __restrict__ XO)
{
  DECL_GEMM_SMEM
  const int z = blockIdx.z;
  const int b = z >> 4;
  mfma_nt_core<0, 1, 0>(P + ((size_t)z << 20), 1024,
                        XVt + (size_t)b * 256 * 1024 + (size_t)(z & 3) * 64 * 1024, 1024,
                        XO + ((size_t)b << 20) + ((size_t)(z & 15) << 6), 1024,
                        1024, nullptr,
                        blockIdx.y << 6, blockIdx.x << 6, Ah, Al, Bh, Bl);
}

// ---------------------------------------------------------------------------
// Monotonic recurrence, 4-WAVE column-split diagonal wavefront (R21).
// ONE 256-thread block per z. Logical lane u = tid owns cols [4u, 4u+4);
// wave w = u>>6. At step s, lane u handles rows 4g..4g+3, g = s - u:
//   phi[r,c] = b[c] + q[r,c-1]*phi[r,c-1]        (1 fma)
//   b[c]     = fma(-q[r,c], phi[r,c], phi[r,c])  (= phi*p, 1 fma)
// Boundary col 4u-1: intra-wave via 8 __shfl_up(.,1); inter-wave (l==0)
// via 8 floats in double-buffered LDS + one raw barrier/step (MONO_BAR,
// R17-proven: lgkmcnt(0)+s_barrier, NO vmcnt drain).
// Per wave per step: 4 float4 loads (prefetch slot s+1) + 4 float4 stores.
// Cross-lane = __shfl only (DPP failed 3x on gfx950 -- permanently banned).
// ---------------------------------------------------------------------------
#define MONO_BAR() do {                                          \
    asm volatile("s_waitcnt lgkmcnt(0)" ::: "memory");           \
    __builtin_amdgcn_sched_barrier(0);                           \
    asm volatile("s_barrier" ::: "memory");                      \
    __builtin_amdgcn_sched_barrier(0);                           \
  } while (0)

__global__ __launch_bounds__(256, 1) void mono_rec_k(float* __restrict__ P)
{
  const int z = blockIdx.x;
  float* __restrict__ Pz = P + ((size_t)z << 20);
  const int tid = threadIdx.x;
  const int u = tid;             // logical lane 0..255
  const int w = tid >> 6;        // wave 0..3
  const int l = tid & 63;        // lane within wave

  __shared__ float BndP[2][3][4];   // [s&1][publisher wave 0..2][row k]
  __shared__ float BndQ[2][3][4];

  float b[4];                    // carry: b[c] = phi[r-1,c] * p[r-1,c]
#pragma unroll
  for (int c = 0; c < 4; ++c) b[c] = 0.0f;
  float phi3h[4], q3h[4];        // col-3 values of the 4 rows (for u+1)
#pragma unroll
  for (int k = 0; k < 4; ++k) { phi3h[k] = 0.0f; q3h[k] = 0.0f; }

  float pA[4][4], pB[4][4];      // q ping-pong (4 rows x 4 cols)

  // prologue: load slot 0 into pA
#pragma unroll
  for (int k = 0; k < 4; ++k)
    *(float4*)&pA[k][0] = *(const float4*)(Pz + (k << 10) + (u << 2));

  auto step = [&](int s, float (&pcur)[4][4], float (&pnext)[4][4]) {
    // boundary batch: intra-wave shuffles (unconditional: sources active)
    float phiL[4], qL[4];
#pragma unroll
    for (int k = 0; k < 4; ++k) {
      phiL[k] = __shfl_up(phi3h[k], 1);
      qL[k]   = __shfl_up(q3h[k], 1);
    }
    // inter-wave boundary: wave w-1's lane-63 values from step s-1
    if (l == 0 && w > 0) {
#pragma unroll
      for (int k = 0; k < 4; ++k) {
        phiL[k] = BndP[(s + 1) & 1][w - 1][k];
        qL[k]   = BndQ[(s + 1) & 1][w - 1][k];
      }
    }

    // prefetch slot s+1 (4 coalesced float4 per wave)
    {
      const float* np = Pz + ((size_t)((s + 1) & 255) << 12) + (u << 2);
#pragma unroll
      for (int k = 0; k < 4; ++k)
        *(float4*)&pnext[k][0] = *(const float4*)(np + (k << 10));
    }

    const int g = s - u;
    if (g >= 0 && g < 256) {
      float phim[4][4];
#pragma unroll
      for (int k = 0; k < 4; ++k) {
        const float* qk = pcur[k];
        float* phi = phim[k];
        if (g == 0 && k == 0) {
          // row 0: phi = onehot(global col 0)
#pragma unroll
          for (int c = 0; c < 4; ++c) phi[c] = 0.0f;
          if (u == 0) phi[0] = 1.0f;
        } else {
          const float H0 = (u == 0) ? 0.0f : qL[k];
          float x = fmaf(H0, phiL[k], b[0]);
          phi[0] = x;
#pragma unroll
          for (int c = 1; c < 4; ++c) {
            x = fmaf(qk[c - 1], x, b[c]);
            phi[c] = x;
          }
        }
        // carry (b = phi*p = phi - q*phi) + neighbor holds
#pragma unroll
        for (int c = 0; c < 4; ++c) b[c] = fmaf(-qk[c], phi[c], phi[c]);
        q3h[k]   = qk[3];
        phi3h[k] = phi[3];
      }
      // stores (in-place slot overwrite, coalesced)
      float* sp = Pz + ((size_t)(s & 255) << 12) + (u << 2);
#pragma unroll
      for (int k = 0; k < 4; ++k)
        *(float4*)(sp + (k << 10)) = *(float4*)&phim[k][0];
    }

    // publish boundary for wave w+1 (ring s&1), then barrier
    if (l == 63 && w < 3) {
#pragma unroll
      for (int k = 0; k < 4; ++k) {
        BndP[s & 1][w][k] = phi3h[k];
        BndQ[s & 1][w][k] = q3h[k];
      }
    }
    MONO_BAR();
  };

  // steps 0..511 (valid work ends at s=510; tail prefetches unconsumed)
  for (int s0 = 0; s0 < 512; s0 += 2) {
    step(s0, pA, pB);
    step(s0 + 1, pB, pA);
  }
}

// ---------------------------------------------------------------------------
extern "C" void kernel_launch(void* const* d_in, const int* in_sizes, int n_in,
                              void* d_out, int out_size, void* d_ws, size_t ws_size,
                              hipStream_t stream)
{
  const float* query = (const float*)d_in[0];
  const float* key   = (const float*)d_in[1];
  const float* value = (const float*)d_in[2];
  const float* ipw   = (const float*)d_in[3];   // (1536,1024)
  const float* ipb   = (const float*)d_in[4];   // (1536,)
  const float* opw   = (const float*)d_in[5];   // (1024,1024)
  const float* opb   = (const float*)d_in[6];   // (1024,)
  float* out = (float*)d_out;
  float* ws  = (float*)d_ws;

  float* XQ  = ws + OFF_XQ;
  float* XK  = ws + OFF_XK;
  float* XVt = ws + OFF_XVT;
  float* XO  = ws + OFF_XO;
  float* P   = ws + OFF_P;

  // fused in-projections: XQ + XK + XVt in one 768-block launch
  inproj_k<<<dim3(768), 256, 0, stream>>>(
      query, key, value, ipw, ipb, XQ, XK, XVt);

  // scores + sigmoid + clip -> q = 1-p (group-diagonal-4 layout)
  scores_mfma_k<<<dim3(16, 16, 32), 256, 0, stream>>>(XQ, XK, P);

  // monotonic recurrence in place (4-wave column split, one block per z)
  mono_rec_k<<<dim3(32), dim3(256), 0, stream>>>(P);

  // phi @ V -> XO (NT against transposed V; A read through diagonal-4 map)
  pv_mfma_k<<<dim3(1, 16, 32), 256, 0, stream>>>(P, XVt, XO);

  // out-projection
  gemm_nt_mfma_k<<<dim3(16, 32), 256, 0, stream>>>(
      XO, 1024, opw, 1024, opb, out, 1024, 1024);
}

// Round 17
// 482.033 us; speedup vs baseline: 1.0274x; 1.0274x over previous
//
#include <hip/hip_runtime.h>
#include <cstddef>
#include <cstdint>

// Problem constants: EMBED=1024, NUM_HEADS=16, GQA=4, KV_HEADS=4,
// HEAD_DIM=64, KV_EMBED=256, EPS=1e-3, B=2, T=1024.
#define TSEQ 1024

typedef __attribute__((ext_vector_type(8))) short short8;   // 8 bf16 = 4 VGPRs
typedef __attribute__((ext_vector_type(4))) float floatx4;  // MFMA acc

// Workspace layout (floats):
//  XQ : 2048 x 1024  (2M)
//  XK : 2048 x 256   (0.5M)
//  XVt: 2 x 256 x 1024 (0.5M)  -- V-projection TRANSPOSED: [b][h*64+c][j]
//  XO : 2048 x 1024  (2M)
//  P  : 32 x 1024x1024 (33.55M) -- q=1-p / phi in GROUP-DIAGONAL layout
static constexpr size_t OFF_XQ  = 0;
static constexpr size_t OFF_XK  = (size_t)2 * 1024 * 1024;
static constexpr size_t OFF_XVT = OFF_XK + (size_t)512 * 1024;
static constexpr size_t OFF_XO  = OFF_XVT + (size_t)512 * 1024;
static constexpr size_t OFF_P   = OFF_XO + (size_t)2 * 1024 * 1024;

// GROUP-DIAGONAL LAYOUT (R10): logical cell (r, c) lives at storage row
//   diagrow(r, c>>4) = (((r>>2) + (c>>4)) & 255)*4 + (r&3).
// R=4 rows per step: lane t owns cols [16t,16t+16), at step s handles
// row-group g = s - t (rows 4g..4g+3). One step = one contiguous 16KB slot
// (slot = s & 255), read and overwritten in place. Wrap bijection: slot
// readers at step m+256 are lanes t>m; its writers at step m were lanes
// t<=m -- disjoint. Scores (CDIAG) writes and PV (ADIAG) reads through the
// same map; per-instruction coalescing preserved.
//
// R22 (final consolidation): the R20 configuration measured 485.85us --
// the session best (796.7 -> 485.85, 1.64x). Resubmitted verbatim.
// Session record on mono_rec: ten structural attacks (single-wave
// prefetch/restrict/reg-budget variants R7-R14, 5-wave producer/consumer
// R15-R18, 4-wave column-split R21) all land in 246-370us; the simple
// R11 single-wave is the floor (246.6us). R21 falsified the last active
// theory (per-wave VMEM count: halving it changed nothing; 512 barriers
// ate the gain). GEMM side (~239us, ~240 TF-equiv MFMA) matches this
// 64x64 structure's shape-curve for these small matrices; the 128x64
// attempt (R19) regressed on occupancy (1 block/CU).
// R20: (a) three in-projections fused into ONE 768-block launch (XK/XVt
// were two half-empty 128-block rounds + two launch gaps); LDS hoisted to
// kernel scope so the three inlined core instances share one 20KB
// allocation. (b) __expf in the sigmoid epilogue.
// R11: q-form recurrence (scores stores q = 1-p), 2 fma/cell.

// ---------------------------------------------------------------------------
// fp32 -> bf16 hi/lo split (RNE). x ≈ hi + lo with residual ~2^-17 |x|.
// ---------------------------------------------------------------------------
__device__ __forceinline__ void cvt_hi_lo(float x, unsigned short& hi,
                                          unsigned short& lo) {
  unsigned u = __float_as_uint(x);
  unsigned rh = (u + 0x7FFFu + ((u >> 16) & 1u)) & 0xFFFF0000u;
  hi = (unsigned short)(rh >> 16);
  float xl = x - __uint_as_float(rh);
  unsigned ul = __float_as_uint(xl);
  unsigned rl = ul + 0x7FFFu + ((ul >> 16) & 1u);
  lo = (unsigned short)(rl >> 16);
}

__device__ __forceinline__ int diagrow(int r, int cblk) {
  return ((((r >> 2) + cblk) & 255) << 2) | (r & 3);
}

typedef unsigned short lds_tile_t[40];

// ---------------------------------------------------------------------------
// Unified NT GEMM core, MFMA bf16x3, 64x64 tile (R5-proven; bm/bn and LDS
// arrays are parameters so fused kernels share one allocation).
// ADIAG: A row index mapped through diagrow. CDIAG: C row through diagrow.
// EPI=2 writes q = sigmoid(-x) clipped (R11), via __expf (R20).
// ---------------------------------------------------------------------------
template <int EPI, int ADIAG, int CDIAG>
__device__ __forceinline__ void mfma_nt_core(
    const float* __restrict__ A, int lda,
    const float* __restrict__ B, int ldb,
    float* __restrict__ C, int ldc, int K,
    const float* __restrict__ bias,
    int bm, int bn,
    lds_tile_t* __restrict__ Ah, lds_tile_t* __restrict__ Al,
    lds_tile_t* __restrict__ Bh, lds_tile_t* __restrict__ Bl)
{
  const int tid  = threadIdx.x;
  const int lane = tid & 63;
  const int wave = tid >> 6;        // 0..3 -> row sub-tile
  const int m16  = lane & 15;
  const int quad = lane >> 4;

  const int srow = tid >> 2;        // staging: row 0..63
  const int skq  = (tid & 3) << 3;  // staging: k offset 0,8,16,24

  floatx4 acc[4];
#pragma unroll
  for (int c = 0; c < 4; ++c) acc[c] = (floatx4){0.f, 0.f, 0.f, 0.f};

  for (int k0 = 0; k0 < K; k0 += 32) {
    {
      const int kq = k0 + skq;
      int arow = bm + srow;
      if (ADIAG) arow = diagrow(arow, kq >> 4);
      const float* ap = A + (size_t)arow * lda + kq;
      const float* bp = B + (size_t)(bn + srow) * ldb + kq;
      float av[8] __attribute__((aligned(16)));
      float bv[8] __attribute__((aligned(16)));
      *(float4*)&av[0] = *(const float4*)(ap);
      *(float4*)&av[4] = *(const float4*)(ap + 4);
      *(float4*)&bv[0] = *(const float4*)(bp);
      *(float4*)&bv[4] = *(const float4*)(bp + 4);
      short8 vah, valo, vbh, vblo;
#pragma unroll
      for (int e = 0; e < 8; ++e) {
        unsigned short h, l;
        cvt_hi_lo(av[e], h, l);
        vah[e] = (short)h; valo[e] = (short)l;
        cvt_hi_lo(bv[e], h, l);
        vbh[e] = (short)h; vblo[e] = (short)l;
      }
      *(short8*)&Ah[srow][skq] = vah;
      *(short8*)&Al[srow][skq] = valo;
      *(short8*)&Bh[srow][skq] = vbh;
      *(short8*)&Bl[srow][skq] = vblo;
    }
    __syncthreads();

    const int arow = (wave << 4) + m16;
    const short8 a_h = *(const short8*)&Ah[arow][quad << 3];
    const short8 a_l = *(const short8*)&Al[arow][quad << 3];
#pragma unroll
    for (int c = 0; c < 4; ++c) {
      const int brow = (c << 4) + m16;
      const short8 b_h = *(const short8*)&Bh[brow][quad << 3];
      const short8 b_l = *(const short8*)&Bl[brow][quad << 3];
      acc[c] = __builtin_amdgcn_mfma_f32_16x16x32_bf16(a_h, b_h, acc[c], 0, 0, 0);
      acc[c] = __builtin_amdgcn_mfma_f32_16x16x32_bf16(a_h, b_l, acc[c], 0, 0, 0);
      acc[c] = __builtin_amdgcn_mfma_f32_16x16x32_bf16(a_l, b_h, acc[c], 0, 0, 0);
    }
    __syncthreads();
  }

#pragma unroll
  for (int c = 0; c < 4; ++c) {
#pragma unroll
    for (int r = 0; r < 4; ++r) {
      const int row = (wave << 4) + (quad << 2) + r;
      const int col = (c << 4) + m16;
      float v = acc[c][r];
      if (EPI == 0) { if (bias) v += bias[bn + col]; }
      if (EPI == 1) { v += bias[bm + row]; }
      if (EPI == 2) {
        // q = 1 - clip(sigmoid(v)) = clip(sigmoid(-v), 0.001, 0.999)
        v = 1.0f / (1.0f + __expf(v));
        v = fminf(fmaxf(v, 0.001f), 0.999f);
      }
      int crow = bm + row;
      if (CDIAG) crow = diagrow(crow, (bn + col) >> 4);
      C[(size_t)crow * ldc + (bn + col)] = v;
    }
  }
}

#define DECL_GEMM_SMEM                                          \
  __shared__ __align__(16) unsigned short Ah[64][40];           \
  __shared__ __align__(16) unsigned short Al[64][40];           \
  __shared__ __align__(16) unsigned short Bh[64][40];           \
  __shared__ __align__(16) unsigned short Bl[64][40];

// ---------------------------------------------------------------------------
// Fused in-projections (R20): one 768-block launch.
//   blocks [0,512):   XQ  = query @ qw^T + qb      (grid was 16 x 32)
//   blocks [512,640): XK  = key @ kw^T + kb        (grid was 4 x 32)
//   blocks [640,768): XVt = (vw @ value^T) + vb    (grid was 16 x 4 x 2)
// Block-uniform dispatch; single shared 20KB LDS tile set.
// ---------------------------------------------------------------------------
__global__ __launch_bounds__(256) void inproj_k(
    const float* __restrict__ query, const float* __restrict__ key,
    const float* __restrict__ value, const float* __restrict__ ipw,
    const float* __restrict__ ipb,
    float* __restrict__ XQ, float* __restrict__ XK, float* __restrict__ XVt)
{
  DECL_GEMM_SMEM
  const int id = blockIdx.x;
  if (id < 512) {
    // XQ: bn = (id&15)*64, bm = (id>>4)*64
    mfma_nt_core<0, 0, 0>(query, 1024, ipw, 1024, XQ, 1024, 1024, ipb,
                          (id >> 4) << 6, (id & 15) << 6, Ah, Al, Bh, Bl);
  } else if (id < 640) {
    const int j = id - 512;   // bn = (j&3)*64, bm = (j>>2)*64
    mfma_nt_core<0, 0, 0>(key, 1024, ipw + ((size_t)1 << 20), 1024,
                          XK, 256, 1024, ipb + 1024,
                          (j >> 2) << 6, (j & 3) << 6, Ah, Al, Bh, Bl);
  } else {
    const int j = id - 640;   // bx = j&15, by = (j>>4)&3, b = j>>6
    const int b = j >> 6;
    mfma_nt_core<1, 0, 0>(ipw + (size_t)1280 * 1024, 1024,
                          value + ((size_t)b << 20), 1024,
                          XVt + (size_t)b * 256 * 1024, 1024, 1024,
                          ipb + 1280,
                          ((j >> 4) & 3) << 6, (j & 15) << 6, Ah, Al, Bh, Bl);
  }
}

// out-projection (and generic NT GEMM), 64x64 tiles
__global__ __launch_bounds__(256) void gemm_nt_mfma_k(
    const float* __restrict__ A, int lda, const float* __restrict__ W, int ldw,
    const float* __restrict__ bias, float* __restrict__ C, int ldc, int K)
{
  DECL_GEMM_SMEM
  mfma_nt_core<0, 0, 0>(A, lda, W, ldw, C, ldc, K, bias,
                        blockIdx.y << 6, blockIdx.x << 6, Ah, Al, Bh, Bl);
}

// scores: writes q = 1-p in GROUP-DIAGONAL layout (CDIAG=1)
__global__ __launch_bounds__(256) void scores_mfma_k(
    const float* __restrict__ XQ, const float* __restrict__ XK,
    float* __restrict__ P)
{
  DECL_GEMM_SMEM
  const int z = blockIdx.z;
  const int b = z >> 4;
  mfma_nt_core<2, 0, 1>(XQ + ((size_t)b << 20) + ((size_t)(z & 15) << 6), 1024,
                        XK + (size_t)b * TSEQ * 256 + ((size_t)(z & 3) << 6), 256,
                        P + ((size_t)z << 20), 1024, 64, nullptr,
                        blockIdx.y << 6, blockIdx.x << 6, Ah, Al, Bh, Bl);
}

// pv: reads phi (A) from GROUP-DIAGONAL layout (ADIAG=1)
__global__ __launch_bounds__(256) void pv_mfma_k(
    const float* __restrict__ P, const float* __restrict__ XVt,
    float* __restrict__ XO)
{
  DECL_GEMM_SMEM
  const int z = blockIdx.z;
  const int b = z >> 4;
  mfma_nt_core<0, 1, 0>(P + ((size_t)z << 20), 1024,
                        XVt + (size_t)b * 256 * 1024 + (size_t)(z & 3) * 64 * 1024, 1024,
                        XO + ((size_t)b << 20) + ((size_t)(z & 15) << 6), 1024,
                        1024, nullptr,
                        blockIdx.y << 6, blockIdx.x << 6, Ah, Al, Bh, Bl);
}

// ---------------------------------------------------------------------------
// Monotonic recurrence, 4-ROW diagonal wavefront in q-form (R11 verbatim --
// the session-best 246us version, re-confirmed R14/R15). ONE WAVE per z.
// Lane t owns cols [16t,16t+16); at step s handles row-group g = s - t:
//   phi[r,c] = b[c] + q[r,c-1]*phi[r,c-1]        (1 fma)
//   b[c]     = fma(-q[r,c], phi[r,c], phi[r,c])  (= phi*p, 1 fma)
// Cross-lane: ONE batch of 8 __shfl_up(.,1) per step (phi15/q15 x 4 rows).
// q for step s+1 prefetched into registers (ping-pong pA/pB).
// Cross-lane = __shfl only (DPP failed 3x on gfx950 -- permanently banned).
// ---------------------------------------------------------------------------
__global__ __launch_bounds__(64) void mono_rec_k(float* __restrict__ P)
{
  const int z = blockIdx.x;
  float* __restrict__ Pz = P + ((size_t)z << 20);
  const int t = threadIdx.x;     // lane 0..63
  const int col0 = t << 4;       // first owned column

  float b[16];                   // carry: b[c] = phi[r-1,c] * p[r-1,c]
#pragma unroll
  for (int c = 0; c < 16; ++c) b[c] = 0.0f;
  float phi15h[4], q15h[4];      // col-15 values of the 4 rows, for lane t+1
#pragma unroll
  for (int k = 0; k < 4; ++k) { phi15h[k] = 0.0f; q15h[k] = 0.0f; }

  float pA[4][16], pB[4][16];    // q ping-pong (4 rows x 16 cols)

  // prologue: load slot 0 into pA
#pragma unroll
  for (int k = 0; k < 4; ++k) {
    const float* lp = Pz + (k << 10) + col0;
#pragma unroll
    for (int q = 0; q < 4; ++q)
      *(float4*)&pA[k][4 * q] = *(const float4*)(lp + 4 * q);
  }

  auto step = [&](int s, float (&pcur)[4][16], float (&pnext)[4][16]) {
    // boundary batch from lane t-1 first (latency overlaps prefetch issue).
    // Unconditional so source lanes are active in the shuffle.
    float phiL[4], qL[4];
#pragma unroll
    for (int k = 0; k < 4; ++k) {
      phiL[k] = __shfl_up(phi15h[k], 1);
      qL[k]   = __shfl_up(q15h[k], 1);
    }

    // prefetch next step's slot (never aliases in-flight stores: slots
    // s-1, s vs (s+1)&255 are distinct; wrap-overlap lanes are invalid)
    {
      const float* np = Pz + ((size_t)((s + 1) & 255) << 12) + col0;
#pragma unroll
      for (int k = 0; k < 4; ++k)
#pragma unroll
        for (int q = 0; q < 4; ++q)
          *(float4*)&pnext[k][4 * q] = *(const float4*)(np + (k << 10) + 4 * q);
    }

    const int g = s - t;
    if (g >= 0 && g < 256) {
      float* sp = Pz + ((size_t)(s & 255) << 12) + col0;
      float phi[16];
#pragma unroll
      for (int k = 0; k < 4; ++k) {
        const float* qk = pcur[k];
        if (g == 0 && k == 0) {
          // row 0: phi = onehot(col 0)
#pragma unroll
          for (int c = 0; c < 16; ++c) phi[c] = 0.0f;
          if (t == 0) phi[0] = 1.0f;
        } else {
          const float H0 = (t == 0) ? 0.0f : qL[k];
          float x = fmaf(H0, phiL[k], b[0]);
          phi[0] = x;
#pragma unroll
          for (int c = 1; c < 16; ++c) {
            x = fmaf(qk[c - 1], x, b[c]);
            phi[c] = x;
          }
        }
        // carry for next row (b = phi*p = phi - q*phi) + neighbor holds
#pragma unroll
        for (int c = 0; c < 16; ++c) b[c] = fmaf(-qk[c], phi[c], phi[c]);
        q15h[k]   = qk[15];
        phi15h[k] = phi[15];
        // write phi over q's cells (in-place, coalesced)
#pragma unroll
        for (int q = 0; q < 4; ++q)
          *(float4*)(sp + (k << 10) + 4 * q) = *(float4*)&phi[4 * q];
      }
    }
  };

  for (int s0 = 0; s0 < 320; s0 += 2) {
    step(s0, pA, pB);
    step(s0 + 1, pB, pA);
  }
}

// ---------------------------------------------------------------------------
extern "C" void kernel_launch(void* const* d_in, const int* in_sizes, int n_in,
                              void* d_out, int out_size, void* d_ws, size_t ws_size,
                              hipStream_t stream)
{
  const float* query = (const float*)d_in[0];
  const float* key   = (const float*)d_in[1];
  const float* value = (const float*)d_in[2];
  const float* ipw   = (const float*)d_in[3];   // (1536,1024)
  const float* ipb   = (const float*)d_in[4];   // (1536,)
  const float* opw   = (const float*)d_in[5];   // (1024,1024)
  const float* opb   = (const float*)d_in[6];   // (1024,)
  float* out = (float*)d_out;
  float* ws  = (float*)d_ws;

  float* XQ  = ws + OFF_XQ;
  float* XK  = ws + OFF_XK;
  float* XVt = ws + OFF_XVT;
  float* XO  = ws + OFF_XO;
  float* P   = ws + OFF_P;

  // fused in-projections: XQ + XK + XVt in one 768-block launch
  inproj_k<<<dim3(768), 256, 0, stream>>>(
      query, key, value, ipw, ipb, XQ, XK, XVt);

  // scores + sigmoid + clip -> q = 1-p (group-diagonal layout)
  scores_mfma_k<<<dim3(16, 16, 32), 256, 0, stream>>>(XQ, XK, P);

  // monotonic recurrence in place (R11 single-wave, session best)
  mono_rec_k<<<dim3(32), dim3(64), 0, stream>>>(P);

  // phi @ V -> XO (NT against transposed V; A read through diagonal map)
  pv_mfma_k<<<dim3(1, 16, 32), 256, 0, stream>>>(P, XVt, XO);

  // out-projection
  gemm_nt_mfma_k<<<dim3(16, 32), 256, 0, stream>>>(
      XO, 1024, opw, 1024, opb, out, 1024, 1024);
}